// Round 1
// 331.318 us; speedup vs baseline: 1.0163x; 1.0163x over previous
//
#include <hip/hip_runtime.h>
#include <hip/hip_bf16.h>
#include <hip/hip_fp16.h>

#define SEQ    2048
#define DMODEL 2048
#define NH     16
#define NKV    4
#define HD     128
#define NTOT   3072   // DMODEL + 2*NKV*HD
#define MROWS  4096   // B*SEQ

typedef __attribute__((ext_vector_type(4))) float f32x4;
typedef __attribute__((ext_vector_type(8))) __bf16 bf16x8;
typedef __attribute__((ext_vector_type(8))) unsigned short u16x8;
typedef __attribute__((ext_vector_type(4))) unsigned short u16x4;

__device__ __forceinline__ void async_copy16(const void* g, void* l) {
  __builtin_amdgcn_global_load_lds(
      (const __attribute__((address_space(1))) void*)g,
      (__attribute__((address_space(3))) void*)l, 16, 0, 0);
}

__device__ __forceinline__ unsigned short fto16(float f) {
  __hip_bfloat16 h = __float2bfloat16(f);
  return *(unsigned short*)&h;
}

__device__ __forceinline__ float b2f(unsigned short u) {
  unsigned int t = (unsigned int)u << 16;
  float f;
  __builtin_memcpy(&f, &t, 4);
  return f;
}

// ---------------- fake-quant (all 4 weights in one launch) ----------------
__global__ __launch_bounds__(256) void fq_kernel(const float* __restrict__ Wq,
                                                 const float* __restrict__ Wk,
                                                 const float* __restrict__ Wv,
                                                 const float* __restrict__ Wp,
                                                 unsigned short* __restrict__ Wcat,
                                                 unsigned short* __restrict__ Wpq) {
  int g = blockIdx.x * 4 + (threadIdx.x >> 6);
  int lane = threadIdx.x & 63;
  const float* W;
  unsigned short* out;
  int blk;
  if (g < 32768)      { W = Wq; out = Wcat;                          blk = g; }
  else if (g < 40960) { W = Wk; out = Wcat + (size_t)2048 * 2048;    blk = g - 32768; }
  else if (g < 49152) { W = Wv; out = Wcat + (size_t)2560 * 2048;    blk = g - 40960; }
  else                { W = Wp; out = Wpq;                           blk = g - 49152; }
  const float* p = W + (size_t)blk * 128 + lane * 2;
  float w0 = p[0], w1 = p[1];
  float m = fmaxf(fabsf(w0), fabsf(w1));
#pragma unroll
  for (int o = 32; o; o >>= 1) m = fmaxf(m, __shfl_xor(m, o));
  float s = fmaxf(m / 31.0f, 1e-12f);
  s = __half2float(__float2half(s));        // fp16 RNE round of scale
  s = fmaxf(s, 6.103515625e-05f);           // fp16 tiny
  float q0 = rintf(fminf(fmaxf(w0 / s, -32.0f), 31.0f)) * s;
  float q1 = rintf(fminf(fmaxf(w1 / s, -32.0f), 31.0f)) * s;
  unsigned short* o16 = out + (size_t)blk * 128 + lane * 2;
  o16[0] = fto16(q0);
  o16[1] = fto16(q1);
}

// ---------------- fp32 -> bf16 convert ----------------
__global__ __launch_bounds__(256) void conv_kernel(const float* __restrict__ in,
                                                   unsigned short* __restrict__ out,
                                                   int n) {
  int i = (blockIdx.x * blockDim.x + threadIdx.x) * 4;
  if (i >= n) return;
  float4 v = *(const float4*)(in + i);
  ushort4 o;
  o.x = fto16(v.x); o.y = fto16(v.y); o.z = fto16(v.z); o.w = fto16(v.w);
  *(ushort4*)(out + i) = o;
}

// ---------------- bf16 MFMA GEMM, C[m,n] = sum_k A[m,k]*B[n,k] ----------------
#define BM 128
#define BN 128
#define BK 32
template <typename OT>
__global__ __launch_bounds__(256) void gemm_bt(const unsigned short* __restrict__ A,
                                               const unsigned short* __restrict__ Bm,
                                               OT* __restrict__ C,
                                               int M, int N, int K) {
  __shared__ unsigned short As[BM * BK];
  __shared__ unsigned short Bs[BN * BK];
  const int tid = threadIdx.x;
  const int wave = tid >> 6, lane = tid & 63;
  const int quad = lane >> 4, l16 = lane & 15;
  const int m0 = blockIdx.x * BM, n0 = blockIdx.y * BN;
  const int wm = (wave >> 1) * 64, wn = (wave & 1) * 64;
  const int sr = lane >> 2, sc = (lane & 3) * 8;

  const unsigned short* Ag = A + (size_t)m0 * K;
  const unsigned short* Bg = Bm + (size_t)n0 * K;

  f32x4 acc[4][4];
#pragma unroll
  for (int i = 0; i < 4; i++)
#pragma unroll
    for (int j = 0; j < 4; j++) acc[i][j] = f32x4{0.f, 0.f, 0.f, 0.f};

  const int seg0 = wave * 2, seg1 = wave * 2 + 1;
  unsigned short* lA0 = &As[seg0 * 16 * BK];
  unsigned short* lA1 = &As[seg1 * 16 * BK];
  unsigned short* lB0 = &Bs[seg0 * 16 * BK];
  unsigned short* lB1 = &Bs[seg1 * 16 * BK];
  const unsigned short* gA0 = Ag + (size_t)(seg0 * 16 + sr) * K + sc;
  const unsigned short* gA1 = Ag + (size_t)(seg1 * 16 + sr) * K + sc;
  const unsigned short* gB0 = Bg + (size_t)(seg0 * 16 + sr) * K + sc;
  const unsigned short* gB1 = Bg + (size_t)(seg1 * 16 + sr) * K + sc;

  for (int k0 = 0; k0 < K; k0 += BK) {
    __syncthreads();
    async_copy16(gA0 + k0, lA0);
    async_copy16(gA1 + k0, lA1);
    async_copy16(gB0 + k0, lB0);
    async_copy16(gB1 + k0, lB1);
    __syncthreads();
    bf16x8 af[4], bf[4];
#pragma unroll
    for (int t = 0; t < 4; t++)
      af[t] = *(const bf16x8*)&As[(wm + t * 16 + l16) * BK + quad * 8];
#pragma unroll
    for (int t = 0; t < 4; t++)
      bf[t] = *(const bf16x8*)&Bs[(wn + t * 16 + l16) * BK + quad * 8];
#pragma unroll
    for (int i = 0; i < 4; i++)
#pragma unroll
      for (int j = 0; j < 4; j++)
        acc[i][j] = __builtin_amdgcn_mfma_f32_16x16x32_bf16(af[i], bf[j], acc[i][j], 0, 0, 0);
  }
#pragma unroll
  for (int i = 0; i < 4; i++) {
    int row_base = m0 + wm + i * 16 + quad * 4;
#pragma unroll
    for (int j = 0; j < 4; j++) {
      int col = n0 + wn + j * 16 + l16;
#pragma unroll
      for (int r = 0; r < 4; r++) {
        if constexpr (sizeof(OT) == 2)
          C[(size_t)(row_base + r) * N + col] = fto16(acc[i][j][r]);
        else
          C[(size_t)(row_base + r) * N + col] = acc[i][j][r];
      }
    }
  }
}

// ---------------- RMSNorm + RoPE + gain (Q,K only), bf16 in/out ----------------
#define QSCALE 0.12751791437524245f   // (1/sqrt(128)) * log2(e)
__global__ __launch_bounds__(256) void normrope_kernel(const unsigned short* __restrict__ qkvb,
                                                       const float* __restrict__ qgain,
                                                       unsigned short* __restrict__ qbuf,
                                                       unsigned short* __restrict__ kbuf) {
  const int i = blockIdx.x;            // token 0..4095
  const int bz = i >> 11, tok = i & 2047;
  const int wave = threadIdx.x >> 6, lane = threadIdx.x & 63;
  const unsigned short* row = qkvb + (size_t)i * NTOT;

  double invf = pow(10000.0, -(double)(2 * lane) / 128.0);
  float freq = (float)((double)tok * invf);
  float cs = cosf(freq), sn = sinf(freq);

  for (int slot = wave; slot < 20; slot += 4) {
    if (slot < 16) {                   // q heads: norm + rope + gain*scale
      int hh = slot;
      const unsigned short* src = row + hh * HD;
      float x1 = b2f(src[lane]), x2 = b2f(src[lane + 64]);
      float ss = x1 * x1 + x2 * x2;
#pragma unroll
      for (int o = 32; o; o >>= 1) ss += __shfl_xor(ss, o);
      float rn = rsqrtf(ss * (1.0f / 128.0f) + 1.1920929e-07f);
      float n1 = x1 * rn, n2 = x2 * rn;
      float g = qgain[hh] * QSCALE;
      unsigned short* dst = qbuf + ((size_t)(bz * NH + hh) * SEQ + tok) * HD;
      dst[lane]      = fto16((n1 * cs + n2 * sn) * g);
      dst[lane + 64] = fto16((-n1 * sn + n2 * cs) * g);
    } else {                           // k heads: norm + rope
      int hh = slot - 16;
      const unsigned short* src = row + DMODEL + hh * HD;
      float x1 = b2f(src[lane]), x2 = b2f(src[lane + 64]);
      float ss = x1 * x1 + x2 * x2;
#pragma unroll
      for (int o = 32; o; o >>= 1) ss += __shfl_xor(ss, o);
      float rn = rsqrtf(ss * (1.0f / 128.0f) + 1.1920929e-07f);
      float n1 = x1 * rn, n2 = x2 * rn;
      unsigned short* dst = kbuf + ((size_t)(bz * NKV + hh) * SEQ + tok) * HD;
      dst[lane]      = fto16(n1 * cs + n2 * sn);
      dst[lane + 64] = fto16(-n1 * sn + n2 * cs);
    }
  }
}

// ---------------- V transpose: bf16 qkv v-section -> bf16 V^T [b,kvh,d,s] ----------------
__global__ __launch_bounds__(256) void vtrans_kernel(const unsigned short* __restrict__ qkvb,
                                                     unsigned short* __restrict__ vtb) {
  __shared__ unsigned short T[64 * 72];
  const int s0 = blockIdx.x * 64;
  const int d0 = blockIdx.y * 64;
  const int bz = blockIdx.z >> 2, h = blockIdx.z & 3;
  const int tid = threadIdx.x;
#pragma unroll
  for (int i = 0; i < 2; ++i) {
    int c = i * 256 + tid;
    int s = c >> 3, ch = c & 7;
    const unsigned short* src =
        qkvb + (size_t)(bz * SEQ + s0 + s) * NTOT + DMODEL + 512 + h * HD + d0 + ch * 8;
    *(u16x8*)&T[s * 72 + ch * 8] = *(const u16x8*)src;
  }
  __syncthreads();
  unsigned short* outg = vtb + (size_t)(bz * NKV + h) * HD * SEQ;
#pragma unroll
  for (int i = 0; i < 2; ++i) {
    int c = i * 256 + tid;
    int d = c >> 3, sc = c & 7;
    u16x8 v;
#pragma unroll
    for (int j = 0; j < 8; ++j) v[j] = T[(sc * 8 + j) * 72 + d];
    *(u16x8*)(outg + (size_t)(d0 + d) * SEQ + s0 + sc * 8) = v;
  }
}

// ---------------- flash attention: 128-row Q tile, 8 waves (16 rows/wave), ----
// XOR-swizzled LDS, O^T form. 512 threads/block so the causal-imbalance tail
// runs with 2+ waves/SIMD instead of 1 (occupancy was the measured bottleneck).
// LDS layouts (flat strides are multiples of 32 dwords -> bank = f(granule only)):
//   Ks[row(kpos)][d]  : elem = row*128 + ((g ^ (row&15))<<3) + (d&7),  g = d>>3
//   Vt[d][kpos]       : elem = d*64   + ((g ^ (d&7))<<3)   + (kp&7),  g = kp>>3
//   Ps[wave][rq][kpos]: elem = rq*64  + ((g ^ (rq&7))<<3)  + (kp&7),  g = kp>>3
__global__ __launch_bounds__(512, 4) void attn_kernel(const unsigned short* __restrict__ qb,
                                                      const unsigned short* __restrict__ kb,
                                                      const unsigned short* __restrict__ vtb,
                                                      unsigned short* __restrict__ yb) {
  __shared__ unsigned short Ks[64 * 128];     // 16 KB
  __shared__ unsigned short Vt[128 * 64];     // 16 KB
  __shared__ unsigned short Ps[8][16 * 64];   // 16 KB

  const int bx = blockIdx.x;
  const int h = blockIdx.y;
  const int bz = blockIdx.z;
  const int qt = bz ? bx : (15 - bx);     // bz-pairing: CU partner gets 15-qt
  const int tid = threadIdx.x;
  const int wave = tid >> 6, lane = tid & 63;
  const int quad = lane >> 4, l16 = lane & 15;
  const int q0 = qt * 128;
  const int base = q0 + wave * 16;        // this wave's 16-row group
  const int kdiag = base >> 6;

  const unsigned short* qg = qb + (size_t)(bz * NH + h) * SEQ * HD;
  const unsigned short* kg = kb + (size_t)(bz * NKV + (h >> 2)) * SEQ * HD;
  const unsigned short* vg = vtb + (size_t)(bz * NKV + (h >> 2)) * HD * SEQ;
  unsigned short* psw = &Ps[wave][0];

  bf16x8 qf[4];
#pragma unroll
  for (int ds = 0; ds < 4; ++ds)
    qf[ds] = *(const bf16x8*)(qg + (size_t)(base + l16) * HD + ds * 32 + quad * 8);

  f32x4 oacc[8];
#pragma unroll
  for (int j = 0; j < 8; ++j) oacc[j] = f32x4{0.f, 0.f, 0.f, 0.f};
  float m_i = -__builtin_inff();
  float l_i = 0.f;

  // staging thread mapping (512 threads)
  const int krw = tid >> 4, kgr = tid & 15;   // K: 32 rows/iter, 16 granules/row
  const int vdw = tid >> 3, vgr = tid & 7;    // V: 64 d/iter, 8 granules/row

  const int nkt = 2 * qt + 2;

  u16x8 pk[2], pv[2];
#pragma unroll
  for (int i = 0; i < 2; ++i)
    pk[i] = *(const u16x8*)(kg + (size_t)(i * 32 + krw) * HD + kgr * 8);
#pragma unroll
  for (int i = 0; i < 2; ++i)
    pv[i] = *(const u16x8*)(vg + (size_t)(i * 64 + vdw) * SEQ + vgr * 8);

  for (int kt = 0; kt < nkt; ++kt) {
#pragma unroll
    for (int i = 0; i < 2; ++i) {
      int row = i * 32 + krw;
      *(u16x8*)&Ks[row * 128 + ((kgr ^ (row & 15)) << 3)] = pk[i];
    }
#pragma unroll
    for (int i = 0; i < 2; ++i) {
      int d = i * 64 + vdw;
      *(u16x8*)&Vt[d * 64 + ((vgr ^ (d & 7)) << 3)] = pv[i];
    }
    __syncthreads();

    if (kt + 1 < nkt) {                  // prefetch next tile into regs
#pragma unroll
      for (int i = 0; i < 2; ++i)
        pk[i] = *(const u16x8*)(kg + (size_t)((kt + 1) * 64 + i * 32 + krw) * HD + kgr * 8);
#pragma unroll
      for (int i = 0; i < 2; ++i)
        pv[i] = *(const u16x8*)(vg + (size_t)(i * 64 + vdw) * SEQ + (kt + 1) * 64 + vgr * 8);
    }

    if (kt <= kdiag) {
      // ---- S^T = K * Q^T ----
      f32x4 st[4];
#pragma unroll
      for (int mt = 0; mt < 4; ++mt) st[mt] = f32x4{0.f, 0.f, 0.f, 0.f};
#pragma unroll
      for (int mt = 0; mt < 4; ++mt)
#pragma unroll
        for (int ds = 0; ds < 4; ++ds) {
          bf16x8 kf = *(const bf16x8*)&Ks[(mt * 16 + l16) * 128 + ((((ds << 2) + quad) ^ l16) << 3)];
          st[mt] = __builtin_amdgcn_mfma_f32_16x16x32_bf16(kf, qf[ds], st[mt], 0, 0, 0);
        }

      // ---- online softmax (state keyed by l16 = q row) ----
      const int qrow = base + l16;
      float p[4][4];
      float mx = -__builtin_inff();
      if (kt == kdiag) {                 // diagonal tile: causal mask
#pragma unroll
        for (int mt = 0; mt < 4; ++mt)
#pragma unroll
          for (int r = 0; r < 4; ++r) {
            int kp = kt * 64 + mt * 16 + quad * 4 + r;
            float v = (kp <= qrow) ? st[mt][r] : -__builtin_inff();
            p[mt][r] = v;
            mx = fmaxf(mx, v);
          }
      } else {
#pragma unroll
        for (int mt = 0; mt < 4; ++mt)
#pragma unroll
          for (int r = 0; r < 4; ++r) {
            p[mt][r] = st[mt][r];
            mx = fmaxf(mx, st[mt][r]);
          }
      }
      mx = fmaxf(mx, __shfl_xor(mx, 16));
      mx = fmaxf(mx, __shfl_xor(mx, 32));
      float mnew = fmaxf(m_i, mx);
      float rs = 0.f;
#pragma unroll
      for (int mt = 0; mt < 4; ++mt)
#pragma unroll
        for (int r = 0; r < 4; ++r) {
          float e = exp2f(p[mt][r] - mnew);
          p[mt][r] = e;
          rs += e;
        }
      rs += __shfl_xor(rs, 16);
      rs += __shfl_xor(rs, 32);
      if (__any(mnew > m_i)) {           // rescale only when max moved
        float a = exp2f(m_i - mnew);
#pragma unroll
        for (int j = 0; j < 8; ++j) oacc[j] *= a;
        l_i = l_i * a + rs;
      } else {
        l_i += rs;
      }
      m_i = mnew;

      // P store: u16x4 at kp = mt*16+quad*4, row rq = l16 (swizzled)
#pragma unroll
      for (int mt = 0; mt < 4; ++mt) {
        u16x4 w;
#pragma unroll
        for (int r = 0; r < 4; ++r) w[r] = fto16(p[mt][r]);
        int g = mt * 2 + (quad >> 1);
        *(u16x4*)&psw[l16 * 64 + ((g ^ (l16 & 7)) << 3) + (quad & 1) * 4] = w;
      }

      __asm__ volatile("s_waitcnt lgkmcnt(0)" ::: "memory");  // own P writes -> reads

      // ---- O^T += V^T * P^T ----
#pragma unroll
      for (int c = 0; c < 2; ++c) {
        bf16x8 pf = *(const bf16x8*)&psw[l16 * 64 + ((((c << 2) + quad) ^ (l16 & 7)) << 3)];
#pragma unroll
        for (int mt = 0; mt < 8; ++mt) {
          bf16x8 vf = *(const bf16x8*)&Vt[(mt * 16 + l16) * 64 + ((((c << 2) + quad) ^ (l16 & 7)) << 3)];
          oacc[mt] = __builtin_amdgcn_mfma_f32_16x16x32_bf16(vf, pf, oacc[mt], 0, 0, 0);
        }
      }
    }
    __syncthreads();                     // all LDS reads done before next stores
  }

  // epilogue: O^T row = d = mt*16+quad*4+r, col = q = l16; per-lane invl
  {
    float il = 1.0f / l_i;
    int qrow = base + l16;
#pragma unroll
    for (int mt = 0; mt < 8; ++mt) {
      u16x4 o;
#pragma unroll
      for (int r = 0; r < 4; ++r) o[r] = fto16(oacc[mt][r] * il);
      *(u16x4*)&yb[(size_t)(bz * SEQ + qrow) * DMODEL + h * HD + mt * 16 + quad * 4] = o;
    }
  }
}

extern "C" void kernel_launch(void* const* d_in, const int* in_sizes, int n_in,
                              void* d_out, int out_size, void* d_ws, size_t ws_size,
                              hipStream_t stream) {
  (void)in_sizes; (void)n_in; (void)out_size; (void)ws_size;
  const float* x  = (const float*)d_in[0];
  const float* Wq = (const float*)d_in[1];
  const float* Wk = (const float*)d_in[2];
  const float* Wv = (const float*)d_in[3];
  const float* Wp = (const float*)d_in[4];
  const float* qg = (const float*)d_in[5];
  float* out = (float*)d_out;
  char* ws = (char*)d_ws;

  // workspace layout; yb aliases xb (x consumed by GEMM1 before attn writes y)
  unsigned short* xb   = (unsigned short*)(ws + 0);          // 16.78 MB
  unsigned short* Wcat = (unsigned short*)(ws + 16777216);   // 12.58 MB (Wq|Wk|Wv rows)
  unsigned short* Wpq  = (unsigned short*)(ws + 29360128);   // 8.39 MB
  unsigned short* qkvb = (unsigned short*)(ws + 37748736);   // 25.17 MB (bf16 qkv)
  unsigned short* qbuf = (unsigned short*)(ws + 62914560);   // 16.78 MB
  unsigned short* kbuf = (unsigned short*)(ws + 79691776);   // 4.19 MB
  unsigned short* vtb  = (unsigned short*)(ws + 83886080);   // 4.19 MB (V^T)
  unsigned short* yb   = xb;

  fq_kernel<<<81920 / 4, 256, 0, stream>>>(Wq, Wk, Wv, Wp, Wcat, Wpq);
  conv_kernel<<<8388608 / 1024, 256, 0, stream>>>(x, xb, 8388608);
  gemm_bt<unsigned short><<<dim3(32, 24), 256, 0, stream>>>(xb, Wcat, qkvb, MROWS, NTOT, DMODEL);
  normrope_kernel<<<MROWS, 256, 0, stream>>>(qkvb, qg, qbuf, kbuf);
  vtrans_kernel<<<dim3(32, 2, 8), 256, 0, stream>>>(qkvb, vtb);
  attn_kernel<<<dim3(16, NH, 2), 512, 0, stream>>>(qbuf, kbuf, vtb, yb);
  gemm_bt<float><<<dim3(32, 16), 256, 0, stream>>>(yb, Wpq, out, MROWS, DMODEL, DMODEL);
}

// Round 3
// 309.416 us; speedup vs baseline: 1.0882x; 1.0708x over previous
//
#include <hip/hip_runtime.h>
#include <hip/hip_bf16.h>
#include <hip/hip_fp16.h>

#define SEQ    2048
#define DMODEL 2048
#define NH     16
#define NKV    4
#define HD     128
#define NTOT   3072   // DMODEL + 2*NKV*HD
#define MROWS  4096   // B*SEQ

typedef __attribute__((ext_vector_type(4))) float f32x4;
typedef __attribute__((ext_vector_type(8))) __bf16 bf16x8;
typedef __attribute__((ext_vector_type(8))) unsigned short u16x8;
typedef __attribute__((ext_vector_type(4))) unsigned short u16x4;

__device__ __forceinline__ void async_copy16(const void* g, void* l) {
  __builtin_amdgcn_global_load_lds(
      (const __attribute__((address_space(1))) void*)g,
      (__attribute__((address_space(3))) void*)l, 16, 0, 0);
}

__device__ __forceinline__ unsigned short fto16(float f) {
  __hip_bfloat16 h = __float2bfloat16(f);
  return *(unsigned short*)&h;
}

__device__ __forceinline__ float b2f(unsigned short u) {
  unsigned int t = (unsigned int)u << 16;
  float f;
  __builtin_memcpy(&f, &t, 4);
  return f;
}

// ---------------- fake-quant (all 4 weights in one launch) ----------------
__global__ __launch_bounds__(256) void fq_kernel(const float* __restrict__ Wq,
                                                 const float* __restrict__ Wk,
                                                 const float* __restrict__ Wv,
                                                 const float* __restrict__ Wp,
                                                 unsigned short* __restrict__ Wcat,
                                                 unsigned short* __restrict__ Wpq) {
  int g = blockIdx.x * 4 + (threadIdx.x >> 6);
  int lane = threadIdx.x & 63;
  const float* W;
  unsigned short* out;
  int blk;
  if (g < 32768)      { W = Wq; out = Wcat;                          blk = g; }
  else if (g < 40960) { W = Wk; out = Wcat + (size_t)2048 * 2048;    blk = g - 32768; }
  else if (g < 49152) { W = Wv; out = Wcat + (size_t)2560 * 2048;    blk = g - 40960; }
  else                { W = Wp; out = Wpq;                           blk = g - 49152; }
  const float* p = W + (size_t)blk * 128 + lane * 2;
  float w0 = p[0], w1 = p[1];
  float m = fmaxf(fabsf(w0), fabsf(w1));
#pragma unroll
  for (int o = 32; o; o >>= 1) m = fmaxf(m, __shfl_xor(m, o));
  float s = fmaxf(m / 31.0f, 1e-12f);
  s = __half2float(__float2half(s));        // fp16 RNE round of scale
  s = fmaxf(s, 6.103515625e-05f);           // fp16 tiny
  float q0 = rintf(fminf(fmaxf(w0 / s, -32.0f), 31.0f)) * s;
  float q1 = rintf(fminf(fmaxf(w1 / s, -32.0f), 31.0f)) * s;
  unsigned short* o16 = out + (size_t)blk * 128 + lane * 2;
  o16[0] = fto16(q0);
  o16[1] = fto16(q1);
}

// ---------------- fp32 -> bf16 convert ----------------
__global__ __launch_bounds__(256) void conv_kernel(const float* __restrict__ in,
                                                   unsigned short* __restrict__ out,
                                                   int n) {
  int i = (blockIdx.x * blockDim.x + threadIdx.x) * 4;
  if (i >= n) return;
  float4 v = *(const float4*)(in + i);
  ushort4 o;
  o.x = fto16(v.x); o.y = fto16(v.y); o.z = fto16(v.z); o.w = fto16(v.w);
  *(ushort4*)(out + i) = o;
}

// ---------------- bf16 MFMA GEMM, C[m,n] = sum_k A[m,k]*B[n,k] ----------------
// BK=64 (halves barrier drains vs BK=32). As/Bs use a rule-21 involution swizzle:
// linear LDS dest for global_load_lds, pre-swizzled GLOBAL granule, XOR on read.
// Without it the 128B row stride is a 16-way bank conflict on ds_read_b128.
// XCD bijective swizzle: blocks on one XCD share the B weight panel in its L2.
#define BM 128
#define BN 128
#define BK 64
template <typename OT>
__global__ __launch_bounds__(256, 3) void gemm_bt(const unsigned short* __restrict__ A,
                                                  const unsigned short* __restrict__ Bm,
                                                  OT* __restrict__ C,
                                                  int M, int N, int K) {
  __shared__ unsigned short As[BM * BK];   // 16 KB
  __shared__ unsigned short Bs[BN * BK];   // 16 KB
  const int tid = threadIdx.x;
  const int wave = tid >> 6, lane = tid & 63;
  const int quad = lane >> 4, l16 = lane & 15;

  // XCD bijective swizzle (nwg % 8 == 0 for both launches: 768, 512)
  int wg = blockIdx.y * gridDim.x + blockIdx.x;
  int nwg = gridDim.x * gridDim.y;
  int cpx = nwg >> 3;
  int swz = (wg & 7) * cpx + (wg >> 3);
  int bxs = swz % gridDim.x, bys = swz / gridDim.x;
  const int m0 = bxs * BM, n0 = bys * BN;
  const int wm = (wave >> 1) * 64, wn = (wave & 1) * 64;

  const unsigned short* Ag = A + (size_t)m0 * K;
  const unsigned short* Bg = Bm + (size_t)n0 * K;

  f32x4 acc[4][4];
#pragma unroll
  for (int i = 0; i < 4; i++)
#pragma unroll
    for (int j = 0; j < 4; j++) acc[i][j] = f32x4{0.f, 0.f, 0.f, 0.f};

  // staging: copy c stages rows c*32..c*32+31; thread covers row tid>>3.
  // Source granule pre-swizzled: (lane&7) ^ (row&7), row&7 == lane>>3 (uniform in c,wave).
  const int srow = tid >> 3;
  const int sg8 = (((lane & 7) ^ (lane >> 3))) * 8;
  const unsigned short* gA = Ag + (size_t)srow * K + sg8;
  const unsigned short* gB = Bg + (size_t)srow * K + sg8;
  unsigned short* lA = &As[wave * 512];    // wave-uniform; HW scatters lane*16B
  unsigned short* lB = &Bs[wave * 512];

  for (int k0 = 0; k0 < K; k0 += BK) {
    __syncthreads();
#pragma unroll
    for (int c = 0; c < 4; ++c) async_copy16(gA + (size_t)c * 32 * K + k0, lA + c * 2048);
#pragma unroll
    for (int c = 0; c < 4; ++c) async_copy16(gB + (size_t)c * 32 * K + k0, lB + c * 2048);
    __syncthreads();
#pragma unroll
    for (int kk = 0; kk < 2; ++kk) {
      bf16x8 af[4], bf[4];
#pragma unroll
      for (int t = 0; t < 4; t++)
        af[t] = *(const bf16x8*)&As[(wm + t * 16 + l16) * BK + ((((kk << 2) + quad) ^ (l16 & 7)) << 3)];
#pragma unroll
      for (int t = 0; t < 4; t++)
        bf[t] = *(const bf16x8*)&Bs[(wn + t * 16 + l16) * BK + ((((kk << 2) + quad) ^ (l16 & 7)) << 3)];
#pragma unroll
      for (int i = 0; i < 4; i++)
#pragma unroll
        for (int j = 0; j < 4; j++)
          acc[i][j] = __builtin_amdgcn_mfma_f32_16x16x32_bf16(af[i], bf[j], acc[i][j], 0, 0, 0);
    }
  }
#pragma unroll
  for (int i = 0; i < 4; i++) {
    int row_base = m0 + wm + i * 16 + quad * 4;
#pragma unroll
    for (int j = 0; j < 4; j++) {
      int col = n0 + wn + j * 16 + l16;
#pragma unroll
      for (int r = 0; r < 4; r++) {
        if constexpr (sizeof(OT) == 2)
          C[(size_t)(row_base + r) * N + col] = fto16(acc[i][j][r]);
        else
          C[(size_t)(row_base + r) * N + col] = acc[i][j][r];
      }
    }
  }
}

// ---------------- RMSNorm + RoPE + gain (Q,K only), bf16 in/out ----------------
#define QSCALE 0.12751791437524245f   // (1/sqrt(128)) * log2(e)
__global__ __launch_bounds__(256) void normrope_kernel(const unsigned short* __restrict__ qkvb,
                                                       const float* __restrict__ qgain,
                                                       unsigned short* __restrict__ qbuf,
                                                       unsigned short* __restrict__ kbuf) {
  const int i = blockIdx.x;            // token 0..4095
  const int bz = i >> 11, tok = i & 2047;
  const int wave = threadIdx.x >> 6, lane = threadIdx.x & 63;
  const unsigned short* row = qkvb + (size_t)i * NTOT;

  double invf = pow(10000.0, -(double)(2 * lane) / 128.0);
  float freq = (float)((double)tok * invf);
  float cs = cosf(freq), sn = sinf(freq);

  for (int slot = wave; slot < 20; slot += 4) {
    if (slot < 16) {                   // q heads: norm + rope + gain*scale
      int hh = slot;
      const unsigned short* src = row + hh * HD;
      float x1 = b2f(src[lane]), x2 = b2f(src[lane + 64]);
      float ss = x1 * x1 + x2 * x2;
#pragma unroll
      for (int o = 32; o; o >>= 1) ss += __shfl_xor(ss, o);
      float rn = rsqrtf(ss * (1.0f / 128.0f) + 1.1920929e-07f);
      float n1 = x1 * rn, n2 = x2 * rn;
      float g = qgain[hh] * QSCALE;
      unsigned short* dst = qbuf + ((size_t)(bz * NH + hh) * SEQ + tok) * HD;
      dst[lane]      = fto16((n1 * cs + n2 * sn) * g);
      dst[lane + 64] = fto16((-n1 * sn + n2 * cs) * g);
    } else {                           // k heads: norm + rope
      int hh = slot - 16;
      const unsigned short* src = row + DMODEL + hh * HD;
      float x1 = b2f(src[lane]), x2 = b2f(src[lane + 64]);
      float ss = x1 * x1 + x2 * x2;
#pragma unroll
      for (int o = 32; o; o >>= 1) ss += __shfl_xor(ss, o);
      float rn = rsqrtf(ss * (1.0f / 128.0f) + 1.1920929e-07f);
      float n1 = x1 * rn, n2 = x2 * rn;
      unsigned short* dst = kbuf + ((size_t)(bz * NKV + hh) * SEQ + tok) * HD;
      dst[lane]      = fto16(n1 * cs + n2 * sn);
      dst[lane + 64] = fto16(-n1 * sn + n2 * cs);
    }
  }
}

// ---------------- V transpose: bf16 qkv v-section -> bf16 V^T [b,kvh,d,s] ----------------
__global__ __launch_bounds__(256) void vtrans_kernel(const unsigned short* __restrict__ qkvb,
                                                     unsigned short* __restrict__ vtb) {
  __shared__ unsigned short T[64 * 72];
  const int s0 = blockIdx.x * 64;
  const int d0 = blockIdx.y * 64;
  const int bz = blockIdx.z >> 2, h = blockIdx.z & 3;
  const int tid = threadIdx.x;
#pragma unroll
  for (int i = 0; i < 2; ++i) {
    int c = i * 256 + tid;
    int s = c >> 3, ch = c & 7;
    const unsigned short* src =
        qkvb + (size_t)(bz * SEQ + s0 + s) * NTOT + DMODEL + 512 + h * HD + d0 + ch * 8;
    *(u16x8*)&T[s * 72 + ch * 8] = *(const u16x8*)src;
  }
  __syncthreads();
  unsigned short* outg = vtb + (size_t)(bz * NKV + h) * HD * SEQ;
#pragma unroll
  for (int i = 0; i < 2; ++i) {
    int c = i * 256 + tid;
    int d = c >> 3, sc = c & 7;
    u16x8 v;
#pragma unroll
    for (int j = 0; j < 8; ++j) v[j] = T[(sc * 8 + j) * 72 + d];
    *(u16x8*)(outg + (size_t)(d0 + d) * SEQ + s0 + sc * 8) = v;
  }
}

// ---------------- flash attention: 128-row Q tile, 8 waves (16 rows/wave) ----
// K: double-buffered LDS via DIRECT global_load_lds (pre-swizzled global source,
//    linear LDS dest — rule-21 involution). K(kt+1) is issued between barrier A
//    and barrier B, stays in flight across the whole compute(kt) phase, and is
//    drained by the next iteration's __syncthreads (A) before anyone reads it.
// A = __syncthreads() (full vmcnt+lgkm drain, m97-verified semantics).
// B = s_waitcnt lgkmcnt(0) + raw s_barrier (V writes visible; K stays in flight).
// V: reg-prefetch + swizzled ds_write (single buffer).
// LDS layouts (flat strides are multiples of 32 dwords -> bank = f(granule only)):
//   Ks[b][row(kpos)][d]: elem = row*128 + ((g ^ (row&15))<<3) + (d&7),  g = d>>3
//   Vt[d][kpos]        : elem = d*64   + ((g ^ (d&7))<<3)   + (kp&7),  g = kp>>3
//   Ps[wave][rq][kpos] : elem = rq*64  + ((g ^ (rq&7))<<3)  + (kp&7),  g = kp>>3
__global__ __launch_bounds__(512, 4) void attn_kernel(const unsigned short* __restrict__ qb,
                                                      const unsigned short* __restrict__ kb,
                                                      const unsigned short* __restrict__ vtb,
                                                      unsigned short* __restrict__ yb) {
  __shared__ unsigned short Ks[2][64 * 128];  // 32 KB (dbuf)
  __shared__ unsigned short Vt[128 * 64];     // 16 KB
  __shared__ unsigned short Ps[8][16 * 64];   // 16 KB   -> 64 KB total

  const int bx = blockIdx.x;
  const int h = blockIdx.y;
  const int bz = blockIdx.z;
  const int qt = bz ? bx : (15 - bx);     // bz-pairing: CU partner gets 15-qt
  const int tid = threadIdx.x;
  const int wave = tid >> 6, lane = tid & 63;
  const int quad = lane >> 4, l16 = lane & 15;
  const int q0 = qt * 128;
  const int base = q0 + wave * 16;        // this wave's 16-row group
  const int kdiag = base >> 6;

  const unsigned short* qg = qb + (size_t)(bz * NH + h) * SEQ * HD;
  const unsigned short* kg = kb + (size_t)(bz * NKV + (h >> 2)) * SEQ * HD;
  const unsigned short* vg = vtb + (size_t)(bz * NKV + (h >> 2)) * HD * SEQ;
  unsigned short* psw = &Ps[wave][0];

  bf16x8 qf[4];
#pragma unroll
  for (int ds = 0; ds < 4; ++ds)
    qf[ds] = *(const bf16x8*)(qg + (size_t)(base + l16) * HD + ds * 32 + quad * 8);

  f32x4 oacc[8];
#pragma unroll
  for (int j = 0; j < 8; ++j) oacc[j] = f32x4{0.f, 0.f, 0.f, 0.f};
  float m_i = -__builtin_inff();
  float l_i = 0.f;

  // K direct staging: thread covers row krow0 (+32 for i=1), pre-swizzled granule.
  // LDS dest linear (wave-uniform base + lane*16B): elem = i*4096 + wave*512 + lane*8
  //  -> row = i*32 + wave*4 + (lane>>4), slot = lane&15. Stored global granule is
  //     slot ^ (row&15) so the swizzled kf read returns granule (ds*4+quad).
  const int krow0 = wave * 4 + (lane >> 4);
  const int ksrcg = (lane & 15) ^ (krow0 & 15);
  const unsigned short* kgK = kg + (size_t)krow0 * HD + ksrcg * 8;

  // V staging thread mapping (reg path)
  const int vdw = tid >> 3, vgr = tid & 7;    // 64 d/iter, 8 granules/row

  const int nkt = 2 * qt + 2;

  // prologue: stage K(0) direct, prefetch V(0) to regs
  async_copy16(kgK, &Ks[0][wave * 512]);
  async_copy16(kgK + (size_t)32 * HD, &Ks[0][4096 + wave * 512]);
  u16x8 pv[2];
#pragma unroll
  for (int i = 0; i < 2; ++i)
    pv[i] = *(const u16x8*)(vg + (size_t)(i * 64 + vdw) * SEQ + vgr * 8);

  for (int kt = 0; kt < nkt; ++kt) {
    // (A) full drain + barrier: prev LDS reads done, K(kt) DMA landed, pv(kt) ready
    __syncthreads();
    // V(kt) regs -> LDS (swizzled scatter)
#pragma unroll
    for (int i = 0; i < 2; ++i) {
      int d = i * 64 + vdw;
      *(u16x8*)&Vt[d * 64 + ((vgr ^ (d & 7)) << 3)] = pv[i];
    }
    if (kt + 1 < nkt) {                  // stage K(kt+1): flies across compute(kt)
      const unsigned short* s = kgK + (size_t)(kt + 1) * 64 * HD;
      async_copy16(s, &Ks[(kt + 1) & 1][wave * 512]);
      async_copy16(s + (size_t)32 * HD, &Ks[(kt + 1) & 1][4096 + wave * 512]);
    }
    __asm__ volatile("s_waitcnt lgkmcnt(0)" ::: "memory");  // my V writes visible
    __builtin_amdgcn_sched_barrier(0);
    __asm__ volatile("s_barrier" ::: "memory");  // (B) V staged; K(kt+1) in flight

    if (kt + 1 < nkt) {                  // prefetch V(kt+1) into regs
#pragma unroll
      for (int i = 0; i < 2; ++i)
        pv[i] = *(const u16x8*)(vg + (size_t)(i * 64 + vdw) * SEQ + (kt + 1) * 64 + vgr * 8);
    }

    if (kt <= kdiag) {
      const unsigned short* Kc = Ks[kt & 1];
      // ---- S^T = K * Q^T ----
      f32x4 st[4];
#pragma unroll
      for (int mt = 0; mt < 4; ++mt) st[mt] = f32x4{0.f, 0.f, 0.f, 0.f};
      __builtin_amdgcn_s_setprio(1);
#pragma unroll
      for (int mt = 0; mt < 4; ++mt)
#pragma unroll
        for (int ds = 0; ds < 4; ++ds) {
          bf16x8 kf = *(const bf16x8*)&Kc[(mt * 16 + l16) * 128 + ((((ds << 2) + quad) ^ l16) << 3)];
          st[mt] = __builtin_amdgcn_mfma_f32_16x16x32_bf16(kf, qf[ds], st[mt], 0, 0, 0);
        }
      __builtin_amdgcn_s_setprio(0);

      // ---- online softmax (state keyed by l16 = q row), defer-max THR=8 ----
      const int qrow = base + l16;
      float p[4][4];
      float mx = -__builtin_inff();
      if (kt == kdiag) {                 // diagonal tile: causal mask
#pragma unroll
        for (int mt = 0; mt < 4; ++mt)
#pragma unroll
          for (int r = 0; r < 4; ++r) {
            int kp = kt * 64 + mt * 16 + quad * 4 + r;
            float v = (kp <= qrow) ? st[mt][r] : -__builtin_inff();
            p[mt][r] = v;
            mx = fmaxf(mx, v);
          }
      } else {
#pragma unroll
        for (int mt = 0; mt < 4; ++mt)
#pragma unroll
          for (int r = 0; r < 4; ++r) {
            p[mt][r] = st[mt][r];
            mx = fmaxf(mx, st[mt][r]);
          }
      }
      mx = fmaxf(mx, __shfl_xor(mx, 16));
      mx = fmaxf(mx, __shfl_xor(mx, 32));
      float mnew = (mx > m_i + 8.f) ? mx : m_i;   // defer-max: tolerate p up to 2^8
      float rs = 0.f;
#pragma unroll
      for (int mt = 0; mt < 4; ++mt)
#pragma unroll
        for (int r = 0; r < 4; ++r) {
          float e = exp2f(p[mt][r] - mnew);
          p[mt][r] = e;
          rs += e;
        }
      rs += __shfl_xor(rs, 16);
      rs += __shfl_xor(rs, 32);
      if (mnew != m_i) {                 // rescale only when deferred max moved
        float a = exp2f(m_i - mnew);
#pragma unroll
        for (int j = 0; j < 8; ++j) oacc[j] *= a;
        l_i = l_i * a + rs;
        m_i = mnew;
      } else {
        l_i += rs;
      }

      // P store: u16x4 at kp = mt*16+quad*4, row rq = l16 (swizzled)
#pragma unroll
      for (int mt = 0; mt < 4; ++mt) {
        u16x4 w;
#pragma unroll
        for (int r = 0; r < 4; ++r) w[r] = fto16(p[mt][r]);
        int g = mt * 2 + (quad >> 1);
        *(u16x4*)&psw[l16 * 64 + ((g ^ (l16 & 7)) << 3) + (quad & 1) * 4] = w;
      }

      __asm__ volatile("s_waitcnt lgkmcnt(0)" ::: "memory");  // own P writes -> reads

      // ---- O^T += V^T * P^T ----
      __builtin_amdgcn_s_setprio(1);
#pragma unroll
      for (int c = 0; c < 2; ++c) {
        bf16x8 pf = *(const bf16x8*)&psw[l16 * 64 + ((((c << 2) + quad) ^ (l16 & 7)) << 3)];
#pragma unroll
        for (int mt = 0; mt < 8; ++mt) {
          bf16x8 vf = *(const bf16x8*)&Vt[(mt * 16 + l16) * 64 + ((((c << 2) + quad) ^ (l16 & 7)) << 3)];
          oacc[mt] = __builtin_amdgcn_mfma_f32_16x16x32_bf16(vf, pf, oacc[mt], 0, 0, 0);
        }
      }
      __builtin_amdgcn_s_setprio(0);
    }
  }

  // epilogue: O^T row = d = mt*16+quad*4+r, col = q = l16; per-lane invl
  {
    float il = 1.0f / l_i;
    int qrow = base + l16;
#pragma unroll
    for (int mt = 0; mt < 8; ++mt) {
      u16x4 o;
#pragma unroll
      for (int r = 0; r < 4; ++r) o[r] = fto16(oacc[mt][r] * il);
      *(u16x4*)&yb[(size_t)(bz * SEQ + qrow) * DMODEL + h * HD + mt * 16 + quad * 4] = o;
    }
  }
}

extern "C" void kernel_launch(void* const* d_in, const int* in_sizes, int n_in,
                              void* d_out, int out_size, void* d_ws, size_t ws_size,
                              hipStream_t stream) {
  (void)in_sizes; (void)n_in; (void)out_size; (void)ws_size;
  const float* x  = (const float*)d_in[0];
  const float* Wq = (const float*)d_in[1];
  const float* Wk = (const float*)d_in[2];
  const float* Wv = (const float*)d_in[3];
  const float* Wp = (const float*)d_in[4];
  const float* qg = (const float*)d_in[5];
  float* out = (float*)d_out;
  char* ws = (char*)d_ws;

  // workspace layout; yb aliases xb (x consumed by GEMM1 before attn writes y)
  unsigned short* xb   = (unsigned short*)(ws + 0);          // 16.78 MB
  unsigned short* Wcat = (unsigned short*)(ws + 16777216);   // 12.58 MB (Wq|Wk|Wv rows)
  unsigned short* Wpq  = (unsigned short*)(ws + 29360128);   // 8.39 MB
  unsigned short* qkvb = (unsigned short*)(ws + 37748736);   // 25.17 MB (bf16 qkv)
  unsigned short* qbuf = (unsigned short*)(ws + 62914560);   // 16.78 MB
  unsigned short* kbuf = (unsigned short*)(ws + 79691776);   // 4.19 MB
  unsigned short* vtb  = (unsigned short*)(ws + 83886080);   // 4.19 MB (V^T)
  unsigned short* yb   = xb;

  fq_kernel<<<81920 / 4, 256, 0, stream>>>(Wq, Wk, Wv, Wp, Wcat, Wpq);
  conv_kernel<<<8388608 / 1024, 256, 0, stream>>>(x, xb, 8388608);
  gemm_bt<unsigned short><<<dim3(32, 24), 256, 0, stream>>>(xb, Wcat, qkvb, MROWS, NTOT, DMODEL);
  normrope_kernel<<<MROWS, 256, 0, stream>>>(qkvb, qg, qbuf, kbuf);
  vtrans_kernel<<<dim3(32, 2, 8), 256, 0, stream>>>(qkvb, vtb);
  attn_kernel<<<dim3(16, NH, 2), 512, 0, stream>>>(qbuf, kbuf, vtb, yb);
  gemm_bt<float><<<dim3(32, 16), 256, 0, stream>>>(yb, Wpq, out, MROWS, DMODEL, DMODEL);
}